// Round 4
// baseline (48.855 us; speedup 1.0000x reference)
//
#include <hip/hip_runtime.h>

// x_{i+1} = M x_i + c_i,  M = I + dt*A (constant 3x3),  c_i = dt * B d_i
// 2-kernel segmented linear scan, all global traffic dense/coalesced via LDS staging.
//   K1: block chunk (2048 rows) -> LDS (dense float4); strided-commutative partials
//       + M^(255-t) fixup + shuffle sum -> block total. Extra block builds power tables.
//   K2: chunk -> LDS; per-thread 8-row partials (kept in regs); per-block redundant
//       carry from the 1024 totals (strided-commutative); KS scan; outputs staged in
//       LDS (aliasing dead chunk) and copied out with dense float4 stores.

static constexpr int  TPB   = 256;
static constexpr int  CHUNK = 2048;            // rows per block
static constexpr int  NBLK  = 1024;            // NBLK*CHUNK = 2097152 rows (incl phantom last)
static constexpr long NROW  = 2097152;

// ws layout (floats): [0,3072) block totals; [3072,3072+234) power tables
//   tab[0..72)    Mp:    M^k, k=1..8        (index (k-1)*9)
//   tab[72..144)  powA:  M^(8*2^l), l=0..7  (index 72+l*9)
//   tab[144..234) P2048: M^(2048*2^i), i=0..9 (index 144+i*9); G2 = P2048[8] = M^(2048*256)
#define WS_TOT 0
#define WS_TAB 3072

struct Coef {
    float m00,m02,m11,m12,m20,m21,m22;
    float b00,b01,b10,b13,b24;
};

__device__ __forceinline__ Coef derive(const float* __restrict__ p){
    Coef o;
    const float dt = 3600.0f;
    float Cai=p[0],Cwe=p[1],Cwi=p[2],Re=p[3],Ri=p[4],Rw=p[5],Rg=p[6];
    o.m00 = 1.0f + dt * (-1.0f/Cai*(1.0f/Rg + 1.0f/Ri));
    o.m02 = dt * (1.0f/(Cai*Ri));
    o.m11 = 1.0f + dt * (-1.0f/Cwe*(1.0f/Re + 1.0f/Rw));
    o.m12 = dt * (1.0f/(Cwe*Rw));
    o.m20 = dt * (1.0f/(Cwi*Ri));
    o.m21 = dt * (1.0f/(Cwi*Rw));
    o.m22 = 1.0f + dt * (-1.0f/Cwi*(1.0f/Rw + 1.0f/Ri));
    o.b00 = dt * (1.0f/(Cai*Rg));
    o.b01 = dt * (1.0f/Cai);
    o.b10 = dt * (1.0f/(Cwe*Re));
    o.b13 = dt * (1.0f/Cwe);
    o.b24 = dt * (1.0f/Cwi);
    return o;
}

__device__ __forceinline__ void step(const Coef& C, float& s0, float& s1, float& s2,
                                     float d0, float d1, float d2, float d3, float d4){
    float c0 = fmaf(C.b00, d0, C.b01*(d1+d2));
    float c1 = fmaf(C.b10, d0, C.b13*d3);
    float c2 = C.b24*d4;
    float n0 = fmaf(C.m00, s0, fmaf(C.m02, s2, c0));
    float n1 = fmaf(C.m11, s1, fmaf(C.m12, s2, c1));
    float n2 = fmaf(C.m20, s0, fmaf(C.m21, s1, fmaf(C.m22, s2, c2)));
    s0=n0; s1=n1; s2=n2;
}

__device__ __forceinline__ void mm3(const double* X, const double* Y, double* Z){
    #pragma unroll
    for (int r=0;r<3;++r)
        #pragma unroll
        for (int c=0;c<3;++c)
            Z[r*3+c] = X[r*3+0]*Y[0*3+c] + X[r*3+1]*Y[1*3+c] + X[r*3+2]*Y[2*3+c];
}
__device__ __forceinline__ void msq(double* X){ double T[9]; mm3(X,X,T);
    #pragma unroll
    for (int i=0;i<9;++i) X[i]=T[i]; }

__device__ __forceinline__ void computeM(const float* __restrict__ p, double* Md){
    double Cai=p[0],Cwe=p[1],Cwi=p[2],Re=p[3],Ri=p[4],Rw=p[5],Rg=p[6];
    const double dt = 3600.0;
    Md[0]=1.0 - dt*((1.0/Rg + 1.0/Ri)/Cai); Md[1]=0.0;                              Md[2]=dt/(Cai*Ri);
    Md[3]=0.0;                              Md[4]=1.0 - dt*((1.0/Re + 1.0/Rw)/Cwe); Md[5]=dt/(Cwe*Rw);
    Md[6]=dt/(Cwi*Ri);                      Md[7]=dt/(Cwi*Rw);                      Md[8]=1.0 - dt*((1.0/Rw + 1.0/Ri)/Cwi);
}

// ---------------- K1: block totals + table builder ---------------------------------
__global__ __launch_bounds__(256) void k_tot(const float* __restrict__ d,
                                             const float* __restrict__ p,
                                             float* __restrict__ ws){
    int t = threadIdx.x, b = blockIdx.x;
    if (b == NBLK){                       // dedicated table-builder block
        if (t == 0){
            double A[9], M0[9], T[9];
            computeM(p, M0);
            #pragma unroll
            for (int i=0;i<9;++i) A[i]=M0[i];
            for (int k=1;k<=8;++k){       // Mp: M^1..M^8
                for (int i=0;i<9;++i) ws[WS_TAB + (k-1)*9 + i] = (float)A[i];
                if (k<8){ mm3(M0, A, T); for(int i=0;i<9;++i) A[i]=T[i]; }
            }
            for (int l=0;l<8;++l){        // powA: M^8 .. M^1024
                for (int i=0;i<9;++i) ws[WS_TAB + 72 + l*9 + i] = (float)A[i];
                msq(A);
            }
            for (int i2=0;i2<10;++i2){    // P2048: M^2048 .. M^(2048*512)
                for (int i=0;i<9;++i) ws[WS_TAB + 144 + i2*9 + i] = (float)A[i];
                msq(A);
            }
        }
        return;
    }

    __shared__ float sh[CHUNK*5];         // 40 KB chunk
    __shared__ float Pw[8][9];            // M^(2^i)
    __shared__ float Gg[9];               // M^256
    __shared__ float wred[4][3];

    long base = (long)b * CHUNK;
    const float4* gsrc = (const float4*)(d + base*5);
    float4* sh4 = (float4*)sh;
    float4 stg[10];
    #pragma unroll
    for (int g=0; g<10; ++g) stg[g] = gsrc[g*TPB + t];     // dense coalesced
    if (t == 0){                                            // overlapped with load latency
        double A[9]; computeM(p, A);
        for (int i2=0;i2<8;++i2){
            for (int i=0;i<9;++i) Pw[i2][i] = (float)A[i];
            msq(A);
        }
        for (int i=0;i<9;++i) Gg[i] = (float)A[i];          // M^256
    }
    #pragma unroll
    for (int g=0; g<10; ++g) sh4[g*TPB + t] = stg[g];       // dense LDS writes
    __syncthreads();

    Coef C = derive(p);
    // strided-commutative partial: v = sum_j (M^256)^(7-j) c_{256j+t}
    float v0,v1,v2;
    {
        const float* r = &sh[t*5];
        v0 = fmaf(C.b00, r[0], C.b01*(r[1]+r[2]));
        v1 = fmaf(C.b10, r[0], C.b13*r[3]);
        v2 = C.b24*r[4];
    }
    #pragma unroll
    for (int j=1;j<8;++j){
        const float* r = &sh[(j*TPB + t)*5];                // lane-stride 5 dwords: conflict-free
        float c0 = fmaf(C.b00, r[0], C.b01*(r[1]+r[2]));
        float c1 = fmaf(C.b10, r[0], C.b13*r[3]);
        float c2 = C.b24*r[4];
        float n0 = Gg[0]*v0+Gg[1]*v1+Gg[2]*v2 + c0;
        float n1 = Gg[3]*v0+Gg[4]*v1+Gg[5]*v2 + c1;
        float n2 = Gg[6]*v0+Gg[7]*v1+Gg[8]*v2 + c2;
        v0=n0;v1=n1;v2=n2;
    }
    // fixup: v <- M^(255-t) v  (powers of M commute; order-free bit product)
    int e = 255 - t;
    #pragma unroll
    for (int i2=0;i2<8;++i2){
        float m0 = Pw[i2][0]*v0+Pw[i2][1]*v1+Pw[i2][2]*v2;
        float m1 = Pw[i2][3]*v0+Pw[i2][4]*v1+Pw[i2][5]*v2;
        float m2 = Pw[i2][6]*v0+Pw[i2][7]*v1+Pw[i2][8]*v2;
        bool bit = (e>>i2)&1;
        v0 = bit?m0:v0; v1 = bit?m1:v1; v2 = bit?m2:v2;
    }
    // commutative sum across block
    #pragma unroll
    for (int m=1;m<64;m<<=1){
        v0 += __shfl_xor(v0, m, 64);
        v1 += __shfl_xor(v1, m, 64);
        v2 += __shfl_xor(v2, m, 64);
    }
    int wv = t>>6, ln = t&63;
    if (ln==0){ wred[wv][0]=v0; wred[wv][1]=v1; wred[wv][2]=v2; }
    __syncthreads();
    if (t==0){
        ws[WS_TOT + b*3+0] = wred[0][0]+wred[1][0]+wred[2][0]+wred[3][0];
        ws[WS_TOT + b*3+1] = wred[0][1]+wred[1][1]+wred[2][1]+wred[3][1];
        ws[WS_TOT + b*3+2] = wred[0][2]+wred[1][2]+wred[2][2]+wred[3][2];
    }
}

// ---------------- K2: carry + scan + emit ------------------------------------------
__global__ __launch_bounds__(256) void k_scan(const float* __restrict__ d,
                                              const float* __restrict__ p,
                                              const float* __restrict__ ws,
                                              const float* __restrict__ x0,
                                              float* __restrict__ out){
    __shared__ float BUF[CHUNK*5];        // chunk; later aliased: outstage [0,6148), Sl [8192,8960)
    __shared__ float tab[234];
    __shared__ float wred[4][3];
    __shared__ float carryL[3];

    int t = threadIdx.x, b = blockIdx.x;
    long base = (long)b * CHUNK;
    const float4* gsrc = (const float4*)(d + base*5);
    float4* sh4 = (float4*)BUF;
    float4 stg[10];
    #pragma unroll
    for (int g=0; g<10; ++g) stg[g] = gsrc[g*TPB + t];
    if (t < 234) tab[t] = ws[WS_TAB + t];
    #pragma unroll
    for (int g=0; g<10; ++g) sh4[g*TPB + t] = stg[g];
    __syncthreads();

    Coef C = derive(p);
    // contiguous 8-row segment, keep all partials (zero-init frame)
    float px[8][3];
    {
        float s0=0.f, s1=0.f, s2=0.f;
        #pragma unroll
        for (int j=0;j<8;++j){
            const float* r = &BUF[(8*t + j)*5];
            step(C, s0,s1,s2, r[0],r[1],r[2],r[3],r[4]);
            px[j][0]=s0; px[j][1]=s1; px[j][2]=s2;
        }
    }

    // ---- per-block redundant carry = state at row base (strided-commutative) ----
    float w0=0.f, w1=0.f, w2=0.f;
    if (t < b){
        int e = b-1-t;
        int m = e>>8, u = e&255;
        const float* G2 = &tab[144 + 8*9];                  // M^(2048*256)
        float a0 = ws[WS_TOT + t*3+0], a1 = ws[WS_TOT + t*3+1], a2 = ws[WS_TOT + t*3+2];
        for (int j=1;j<=m;++j){
            int kk = 256*j + t;
            float n0 = G2[0]*a0+G2[1]*a1+G2[2]*a2 + ws[WS_TOT+kk*3+0];
            float n1 = G2[3]*a0+G2[4]*a1+G2[5]*a2 + ws[WS_TOT+kk*3+1];
            float n2 = G2[6]*a0+G2[7]*a1+G2[8]*a2 + ws[WS_TOT+kk*3+2];
            a0=n0;a1=n1;a2=n2;
        }
        #pragma unroll
        for (int i2=0;i2<8;++i2){                           // a <- M^(2048*u) a
            const float* P = &tab[144 + i2*9];
            float m0 = P[0]*a0+P[1]*a1+P[2]*a2;
            float m1 = P[3]*a0+P[4]*a1+P[5]*a2;
            float m2 = P[6]*a0+P[7]*a1+P[8]*a2;
            bool bit = (u>>i2)&1;
            a0 = bit?m0:a0; a1=bit?m1:a1; a2=bit?m2:a2;
        }
        w0=a0; w1=a1; w2=a2;
    }
    if (t == 0){                                            // + M^(2048 b) x0
        float a0=x0[0], a1=x0[1], a2=x0[2];
        #pragma unroll
        for (int i2=0;i2<10;++i2){
            const float* P = &tab[144 + i2*9];
            float m0 = P[0]*a0+P[1]*a1+P[2]*a2;
            float m1 = P[3]*a0+P[4]*a1+P[5]*a2;
            float m2 = P[6]*a0+P[7]*a1+P[8]*a2;
            bool bit = (b>>i2)&1;
            a0 = bit?m0:a0; a1=bit?m1:a1; a2=bit?m2:a2;
        }
        w0+=a0; w1+=a1; w2+=a2;
    }
    #pragma unroll
    for (int m2v=1;m2v<64;m2v<<=1){
        w0 += __shfl_xor(w0, m2v, 64);
        w1 += __shfl_xor(w1, m2v, 64);
        w2 += __shfl_xor(w2, m2v, 64);
    }
    int wv=t>>6, ln=t&63;
    if (ln==0){ wred[wv][0]=w0; wred[wv][1]=w1; wred[wv][2]=w2; }
    __syncthreads();
    if (t==0){
        carryL[0]=wred[0][0]+wred[1][0]+wred[2][0]+wred[3][0];
        carryL[1]=wred[0][1]+wred[1][1]+wred[2][1]+wred[3][1];
        carryL[2]=wred[0][2]+wred[1][2]+wred[2][2]+wred[3][2];
    }
    __syncthreads();
    float c0=carryL[0], c1=carryL[1], c2=carryL[2];

    // ---- KS scan over 256 segment totals (chunk region is dead; Sl aliases it) ----
    float* Sl = &BUF[8192];
    float z0=px[7][0], z1=px[7][1], z2=px[7][2];
    if (t==0){
        const float* M8 = &tab[72];                         // M^8
        z0 += M8[0]*c0+M8[1]*c1+M8[2]*c2;
        z1 += M8[3]*c0+M8[4]*c1+M8[5]*c2;
        z2 += M8[6]*c0+M8[7]*c1+M8[8]*c2;
    }
    Sl[t*3+0]=z0; Sl[t*3+1]=z1; Sl[t*3+2]=z2;
    __syncthreads();
    #pragma unroll
    for (int l=0;l<8;++l){
        const float* P = &tab[72 + l*9];                    // M^(8*2^l)
        int off = 1<<l;
        float y0=0.f,y1=0.f,y2=0.f;
        if (t>=off){ y0=Sl[(t-off)*3+0]; y1=Sl[(t-off)*3+1]; y2=Sl[(t-off)*3+2]; }
        __syncthreads();
        if (t>=off){
            z0 += P[0]*y0+P[1]*y1+P[2]*y2;
            z1 += P[3]*y0+P[4]*y1+P[5]*y2;
            z2 += P[6]*y0+P[7]*y1+P[8]*y2;
            Sl[t*3+0]=z0; Sl[t*3+1]=z1; Sl[t*3+2]=z2;
        }
        __syncthreads();
    }
    float s0,s1,s2;
    if (t==0){ s0=c0; s1=c1; s2=c2; }
    else     { s0=Sl[(t-1)*3+0]; s1=Sl[(t-1)*3+1]; s2=Sl[(t-1)*3+2]; }

    // ---- emit: x_j = px[j] + M^(j+1) * start; stage into LDS, dense copy out ----
    float* ost = BUF;                                       // q in [0, 6148); q = 3*(R+1)+o
    #pragma unroll
    for (int j=0;j<8;++j){
        const float* P = &tab[j*9];                         // M^(j+1)
        float o0 = px[j][0] + P[0]*s0+P[1]*s1+P[2]*s2;
        float o1 = px[j][1] + P[3]*s0+P[4]*s1+P[5]*s2;
        float o2 = px[j][2] + P[6]*s0+P[7]*s1+P[8]*s2;
        int q = 24*t + 3 + 3*j;
        ost[q+0]=o0; ost[q+1]=o1; ost[q+2]=o2;
    }
    __syncthreads();
    float* og = out + base*3;
    const float4* ost4 = (const float4*)ost;
    float4* og4 = (float4*)og;                              // base*3 % 4 == 0 -> aligned
    #pragma unroll
    for (int g=0; g<6; ++g){
        int f = g*TPB + t;
        if (f != 0) og4[f] = ost4[f];                       // dense float4 stores
    }
    if (t == 0){
        og[3] = ost[3];                                     // head dword (q=3)
        if (b == 0){ out[0]=x0[0]; out[1]=x0[1]; out[2]=x0[2]; }
        if (b != NBLK-1){ og[6144]=ost[6144]; og[6145]=ost[6145]; og[6146]=ost[6146]; }
    }
}

extern "C" void kernel_launch(void* const* d_in, const int* in_sizes, int n_in,
                              void* d_out, int out_size, void* d_ws, size_t ws_size,
                              hipStream_t stream) {
    const float* params = (const float*)d_in[0];
    const float* x0     = (const float*)d_in[1];
    const float* d      = (const float*)d_in[2];
    float* out = (float*)d_out;
    float* ws  = (float*)d_ws;     // 3072 totals + 234 table floats (~13 KB)

    k_tot <<<NBLK+1, TPB, 0, stream>>>(d, params, ws);
    k_scan<<<NBLK,   TPB, 0, stream>>>(d, params, ws, x0, out);
}